// Round 1
// baseline (1117.628 us; speedup 1.0000x reference)
//
#include <hip/hip_runtime.h>
#include <math.h>

#define NPTS 32768
#define DD 8
#define OO 20      // ORDER+1
#define PP 20
#define NCHAIN 7   // c=0: mean chain; c=1..6: variance moment k=c

// C(19,q) — exact in fp32 (max 92378 < 2^24)
__device__ __constant__ float c_binom[OO] = {
    1.f, 19.f, 171.f, 969.f, 3876.f, 11628.f, 27132.f, 50388.f, 75582.f, 92378.f,
    92378.f, 75582.f, 50388.f, 27132.f, 11628.f, 3876.f, 969.f, 171.f, 19.f, 1.f};

// ---------------------------------------------------------------------------
// Prep: build exp'd, transposed, binom-folded weights.
//   W0t[c][p][q]       = c==0 ? exp(meanw0[p][q])*binom[q]
//                             : exp(2*meanw0 + c*varw0)*binom[q]^2
//   Wt[c][i][p][q][o]  = c==0 ? exp(meanw[i][p][o][q])*binom[q]
//                             : exp(2*meanw + c*varw)*binom[q]^2
// (gate applies to output index q, so binom folds into weight column q)
// ---------------------------------------------------------------------------
__global__ void prep_kernel(const float* __restrict__ meanw0,
                            const float* __restrict__ meanw,
                            const float* __restrict__ varw0,
                            const float* __restrict__ varw,
                            float* __restrict__ W0t,
                            float* __restrict__ Wt) {
    int e = blockIdx.x * 256 + threadIdx.x;
    const int n0 = NCHAIN * PP * OO;                     // 2800
    const int nW = NCHAIN * (DD - 1) * PP * OO * OO;     // 392000
    if (e < n0) {
        int q = e % OO;
        int rem = e / OO;
        int p = rem % PP;
        int c = rem / PP;
        float m = meanw0[p * OO + q];
        float b = c_binom[q];
        float v;
        if (c == 0) v = __expf(m) * b;
        else        v = __expf(2.f * m + (float)c * varw0[p * OO + q]) * b * b;
        W0t[e] = v;
    } else if (e < n0 + nW) {
        int idx = e - n0;
        int o = idx % OO; idx /= OO;
        int q = idx % OO; idx /= OO;
        int p = idx % PP; idx /= PP;
        int i = idx % (DD - 1);
        int c = idx / (DD - 1);
        int mi = ((i * PP + p) * OO + o) * OO + q;       // meanw[i][p][o][q]
        float m = meanw[mi];
        float b = c_binom[q];
        float v;
        if (c == 0) v = __expf(m) * b;
        else        v = __expf(2.f * m + (float)c * varw[mi]) * b * b;
        Wt[e - n0] = v;
    }
}

// gate g[q] = a^q * b^(19-q) with a=t,b=1-t (mean) or a=t^2,b=(1-t)^2 (var)
__device__ __forceinline__ void make_gate(float tv, bool sq, float* g) {
    float a = tv, b = 1.f - tv;
    if (sq) { a *= a; b *= b; }
    float v = 1.f;
#pragma unroll
    for (int q = 0; q < OO; ++q) { g[q] = v; v *= a; }
    v = 1.f;
#pragma unroll
    for (int q = OO - 1; q >= 0; --q) { g[q] *= v; v *= b; }
}

// ---------------------------------------------------------------------------
// Main: one thread per n, one block-row (blockIdx.y) per (chain c, perm p).
// Weights are wave-uniform -> scalar loads; all math in fp32 on VALU.
// ---------------------------------------------------------------------------
__global__ __launch_bounds__(256) void chain_kernel(
    const float* __restrict__ X, const int* __restrict__ perm,
    const float* __restrict__ W0t, const float* __restrict__ Wt,
    float* __restrict__ partial) {
    int n = blockIdx.x * 256 + threadIdx.x;
    int cp = blockIdx.y;
    int c = cp / PP;
    int p = cp % PP;
    bool sq = (c != 0);

    // permuted X row
    float t[DD];
#pragma unroll
    for (int i = 0; i < DD; ++i) {
        int d = perm[p * DD + i];          // uniform -> s_load
        t[i] = X[n * DD + d];
    }

    float g[OO], f[OO];
    make_gate(t[0], sq, g);
    const float* w0 = W0t + (c * PP + p) * OO;
#pragma unroll
    for (int q = 0; q < OO; ++q) f[q] = w0[q] * g[q];

    for (int i = 1; i < DD; ++i) {
        make_gate(t[i], sq, g);
        const float* w = Wt + (((c * (DD - 1) + (i - 1)) * PP + p) * OO) * OO; // [q][o]
        float fn[OO];
#pragma unroll
        for (int q = 0; q < OO; ++q) {
            float s = 0.f;
#pragma unroll
            for (int o = 0; o < OO; ++o) s = fmaf(f[o], w[q * OO + o], s);
            fn[q] = s * g[q];
        }
#pragma unroll
        for (int q = 0; q < OO; ++q) f[q] = fn[q];
    }

    float tot = 0.f;
#pragma unroll
    for (int q = 0; q < OO; ++q) tot += f[q];
    partial[cp * NPTS + n] = tot;
}

// ---------------------------------------------------------------------------
// Reduce partials: out[n][0] = sum_p mean; out[n][1] = sum_k coef[k] sum_p mom
// ---------------------------------------------------------------------------
__global__ void reduce_kernel(const float* __restrict__ partial,
                              float* __restrict__ out) {
    int n = blockIdx.x * 256 + threadIdx.x;
    float m = 0.f;
#pragma unroll
    for (int p = 0; p < PP; ++p) m += partial[p * NPTS + n];

    const float coef[NCHAIN] = {0.f, 1.f, 0.5f, 1.f / 6.f, 1.f / 24.f,
                                1.f / 120.f, 1.f / 720.f};
    float v = 0.f;
#pragma unroll
    for (int c = 1; c < NCHAIN; ++c) {
        float s = 0.f;
#pragma unroll
        for (int p = 0; p < PP; ++p) s += partial[(c * PP + p) * NPTS + n];
        v += coef[c] * s;
    }
    out[2 * n] = m;
    out[2 * n + 1] = v;
}

extern "C" void kernel_launch(void* const* d_in, const int* in_sizes, int n_in,
                              void* d_out, int out_size, void* d_ws, size_t ws_size,
                              hipStream_t stream) {
    const float* X      = (const float*)d_in[0];
    const int*   perm   = (const int*)d_in[1];
    const float* meanw0 = (const float*)d_in[2];
    const float* meanw  = (const float*)d_in[3];
    const float* varw0  = (const float*)d_in[4];
    const float* varw   = (const float*)d_in[5];
    float* out = (float*)d_out;

    // workspace layout
    float* W0t     = (float*)d_ws;                        // 2800 floats
    float* Wt      = W0t + NCHAIN * PP * OO;              // 392000 floats
    float* partial = Wt + NCHAIN * (DD - 1) * PP * OO * OO; // 140*32768 floats

    int prep_n = NCHAIN * PP * OO + NCHAIN * (DD - 1) * PP * OO * OO;
    hipLaunchKernelGGL(prep_kernel, dim3((prep_n + 255) / 256), dim3(256), 0,
                       stream, meanw0, meanw, varw0, varw, W0t, Wt);

    dim3 grid(NPTS / 256, NCHAIN * PP);
    hipLaunchKernelGGL(chain_kernel, grid, dim3(256), 0, stream,
                       X, perm, W0t, Wt, partial);

    hipLaunchKernelGGL(reduce_kernel, dim3(NPTS / 256), dim3(256), 0, stream,
                       partial, out);
}

// Round 2
// 586.432 us; speedup vs baseline: 1.9058x; 1.9058x over previous
//
#include <hip/hip_runtime.h>
#include <math.h>

#define NPTS 32768
#define DD 8
#define OO 20      // ORDER+1
#define PP 20
#define NCHAIN 7   // c=0: mean chain; c=1..6: variance moment k=c

// C(19,q) — exact in fp32 (max 92378 < 2^24)
__device__ __constant__ float c_binom[OO] = {
    1.f, 19.f, 171.f, 969.f, 3876.f, 11628.f, 27132.f, 50388.f, 75582.f, 92378.f,
    92378.f, 75582.f, 50388.f, 27132.f, 11628.f, 3876.f, 969.f, 171.f, 19.f, 1.f};

// ---------------------------------------------------------------------------
// Prep: exp'd, transposed, binom-folded weights.
//   W0t[c][p][q]      = c==0 ? exp(meanw0[p][q])*binom[q]
//                            : exp(2*meanw0 + c*varw0)*binom[q]^2
//   Wt[c][i][p][q][o] = c==0 ? exp(meanw[i][p][o][q])*binom[q]
//                            : exp(2*meanw + c*varw)*binom[q]^2
// ---------------------------------------------------------------------------
__global__ void prep_kernel(const float* __restrict__ meanw0,
                            const float* __restrict__ meanw,
                            const float* __restrict__ varw0,
                            const float* __restrict__ varw,
                            float* __restrict__ W0t,
                            float* __restrict__ Wt) {
    int e = blockIdx.x * 256 + threadIdx.x;
    const int n0 = NCHAIN * PP * OO;                     // 2800
    const int nW = NCHAIN * (DD - 1) * PP * OO * OO;     // 392000
    if (e < n0) {
        int q = e % OO;
        int rem = e / OO;
        int p = rem % PP;
        int c = rem / PP;
        float m = meanw0[p * OO + q];
        float b = c_binom[q];
        float v;
        if (c == 0) v = __expf(m) * b;
        else        v = __expf(2.f * m + (float)c * varw0[p * OO + q]) * b * b;
        W0t[e] = v;
    } else if (e < n0 + nW) {
        int idx = e - n0;
        int o = idx % OO; idx /= OO;
        int q = idx % OO; idx /= OO;
        int p = idx % PP; idx /= PP;
        int i = idx % (DD - 1);
        int c = idx / (DD - 1);
        int mi = ((i * PP + p) * OO + o) * OO + q;       // meanw[i][p][o][q]
        float m = meanw[mi];
        float b = c_binom[q];
        float v;
        if (c == 0) v = __expf(m) * b;
        else        v = __expf(2.f * m + (float)c * varw[mi]) * b * b;
        Wt[e - n0] = v;
    }
}

// gate g[q] = a^q * b^(19-q); a=t,b=1-t (mean) or a=t^2,b=(1-t)^2 (var)
__device__ __forceinline__ void gate20(float tv, bool sq, float* g) {
    float a = tv, b = 1.f - tv;
    if (sq) { a *= a; b *= b; }
    float v = 1.f;
#pragma unroll
    for (int q = 0; q < OO; ++q) { g[q] = v; v *= a; }
    v = 1.f;
#pragma unroll
    for (int q = OO - 1; q >= 0; --q) { g[q] *= v; v *= b; }
}

// one chain step: fout[q] = (sum_o fin[o]*w[q][o]) * g[q]
// w is wave-uniform (SGPR-addressed); every array index is a constant.
__device__ __forceinline__ void step20(const float* __restrict__ w,
                                       const float* fin, float* fout,
                                       const float* g) {
#pragma unroll
    for (int q = 0; q < OO; ++q) {
        float s = 0.f;
#pragma unroll
        for (int o = 0; o < OO; ++o) s = fmaf(fin[o], w[q * OO + o], s);
        fout[q] = s * g[q];
    }
}

// ---------------------------------------------------------------------------
// Main: one thread per n; blockIdx.y = (chain c, perm p). Fully unrolled
// ping-pong (fA/fB) so nothing spills; 8 named t-scalars (no runtime-indexed
// local array).
// ---------------------------------------------------------------------------
__global__ __launch_bounds__(256) void chain_kernel(
    const float* __restrict__ X, const int* __restrict__ perm,
    const float* __restrict__ W0t, const float* __restrict__ Wt,
    float* __restrict__ partial) {
    int n = blockIdx.x * 256 + threadIdx.x;
    int cp = blockIdx.y;
    int c = cp / PP;
    int p = cp % PP;
    bool sq = (c != 0);

    // uniform perm entries (s_load), then 8 early vector loads of the X row
    int d0 = perm[p * DD + 0], d1 = perm[p * DD + 1];
    int d2 = perm[p * DD + 2], d3 = perm[p * DD + 3];
    int d4 = perm[p * DD + 4], d5 = perm[p * DD + 5];
    int d6 = perm[p * DD + 6], d7 = perm[p * DD + 7];
    const float* xr = X + n * DD;
    float t0 = xr[d0], t1 = xr[d1], t2 = xr[d2], t3 = xr[d3];
    float t4 = xr[d4], t5 = xr[d5], t6 = xr[d6], t7 = xr[d7];

    const float* w0 = W0t + (c * PP + p) * OO;
    const float* wb = Wt + ((c * (DD - 1)) * PP + p) * OO * OO;
    const int wstride = PP * OO * OO;   // step i -> wb + (i-1)*wstride

    float g[OO], fA[OO], fB[OO];
    gate20(t0, sq, g);
#pragma unroll
    for (int q = 0; q < OO; ++q) fA[q] = w0[q] * g[q];

    gate20(t1, sq, g); step20(wb + 0 * wstride, fA, fB, g);
    gate20(t2, sq, g); step20(wb + 1 * wstride, fB, fA, g);
    gate20(t3, sq, g); step20(wb + 2 * wstride, fA, fB, g);
    gate20(t4, sq, g); step20(wb + 3 * wstride, fB, fA, g);
    gate20(t5, sq, g); step20(wb + 4 * wstride, fA, fB, g);
    gate20(t6, sq, g); step20(wb + 5 * wstride, fB, fA, g);
    gate20(t7, sq, g); step20(wb + 6 * wstride, fA, fB, g);

    float tot = 0.f;
#pragma unroll
    for (int q = 0; q < OO; ++q) tot += fB[q];
    partial[cp * NPTS + n] = tot;
}

// ---------------------------------------------------------------------------
// Reduce: out[n][0] = sum_p mean; out[n][1] = sum_k coef[k] sum_p mom_k
// ---------------------------------------------------------------------------
__global__ void reduce_kernel(const float* __restrict__ partial,
                              float* __restrict__ out) {
    int n = blockIdx.x * 256 + threadIdx.x;
    float m = 0.f;
#pragma unroll
    for (int p = 0; p < PP; ++p) m += partial[p * NPTS + n];

    const float coef[NCHAIN] = {0.f, 1.f, 0.5f, 1.f / 6.f, 1.f / 24.f,
                                1.f / 120.f, 1.f / 720.f};
    float v = 0.f;
#pragma unroll
    for (int c = 1; c < NCHAIN; ++c) {
        float s = 0.f;
#pragma unroll
        for (int p = 0; p < PP; ++p) s += partial[(c * PP + p) * NPTS + n];
        v += coef[c] * s;
    }
    out[2 * n] = m;
    out[2 * n + 1] = v;
}

extern "C" void kernel_launch(void* const* d_in, const int* in_sizes, int n_in,
                              void* d_out, int out_size, void* d_ws, size_t ws_size,
                              hipStream_t stream) {
    const float* X      = (const float*)d_in[0];
    const int*   perm   = (const int*)d_in[1];
    const float* meanw0 = (const float*)d_in[2];
    const float* meanw  = (const float*)d_in[3];
    const float* varw0  = (const float*)d_in[4];
    const float* varw   = (const float*)d_in[5];
    float* out = (float*)d_out;

    float* W0t     = (float*)d_ws;                          // 2800 floats
    float* Wt      = W0t + NCHAIN * PP * OO;                // 392000 floats
    float* partial = Wt + NCHAIN * (DD - 1) * PP * OO * OO; // 140*32768 floats

    int prep_n = NCHAIN * PP * OO + NCHAIN * (DD - 1) * PP * OO * OO;
    hipLaunchKernelGGL(prep_kernel, dim3((prep_n + 255) / 256), dim3(256), 0,
                       stream, meanw0, meanw, varw0, varw, W0t, Wt);

    dim3 grid(NPTS / 256, NCHAIN * PP);
    hipLaunchKernelGGL(chain_kernel, grid, dim3(256), 0, stream,
                       X, perm, W0t, Wt, partial);

    hipLaunchKernelGGL(reduce_kernel, dim3(NPTS / 256), dim3(256), 0, stream,
                       partial, out);
}

// Round 4
// 344.132 us; speedup vs baseline: 3.2477x; 1.7041x over previous
//
#include <hip/hip_runtime.h>
#include <math.h>

#define NPTS 32768
#define DD 8
#define OO 20      // ORDER+1
#define PP 20
#define NCHAIN 7   // c=0: mean chain; c=1..6: variance moment k=c

typedef _Float16 half8 __attribute__((ext_vector_type(8)));
typedef __fp16 fp16x2 __attribute__((ext_vector_type(2)));
typedef float floatx16 __attribute__((ext_vector_type(16)));

// ---------------------------------------------------------------------------
// Prep:
//   W0[c][p][q]  fp32, = c==0 ? exp(meanw0) : exp(2*meanw0 + c*varw0)   (no binom)
//   WA[c][i][p][q][o] f16, 32x32 zero-padded, = transposed exp'd weights:
//       q<20,o<20: c==0 ? exp(meanw[i][p][o][q]) : exp(2*m + c*v); else 0
// binom lives in the fp32 gate (binom up to 92378 > f16 max; basis in [0,1]).
// ---------------------------------------------------------------------------
__global__ void prep_kernel(const float* __restrict__ meanw0,
                            const float* __restrict__ meanw,
                            const float* __restrict__ varw0,
                            const float* __restrict__ varw,
                            float* __restrict__ W0,
                            _Float16* __restrict__ WA) {
    int e = blockIdx.x * 256 + threadIdx.x;
    const int n0 = NCHAIN * PP * OO;                 // 2800
    const int nW = NCHAIN * (DD - 1) * PP * 32 * 32; // 1,003,520
    if (e < n0) {
        int q = e % OO;
        int rem = e / OO;
        int p = rem % PP;
        int c = rem / PP;
        float m = meanw0[p * OO + q];
        W0[e] = (c == 0) ? __expf(m) : __expf(2.f * m + (float)c * varw0[p * OO + q]);
    } else if (e < n0 + nW) {
        int idx = e - n0;
        int o = idx & 31; idx >>= 5;
        int q = idx & 31; idx >>= 5;
        int p = idx % PP; idx /= PP;
        int i = idx % (DD - 1);
        int c = idx / (DD - 1);
        float v = 0.f;
        if (o < OO && q < OO) {
            int mi = ((i * PP + p) * OO + o) * OO + q;   // meanw[i][p][o][q]
            float m = meanw[mi];
            v = (c == 0) ? __expf(m) : __expf(2.f * m + (float)c * varw[mi]);
        }
        WA[e - n0] = (_Float16)v;
    }
}

// ---------------------------------------------------------------------------
// gate basis b_q = binom[q] t^q (1-t)^(19-q), selected at the 12 C-reg rows
// this half-wave owns: q = (r&3)+8*(r>>2)+4*hi; hi rows >=20 get 0.
// var chains use basis^2.
// ---------------------------------------------------------------------------
__device__ __forceinline__ void gate_sel(float tv, bool sq, bool hi, float* gs) {
    constexpr float binom[OO] = {
        1.f, 19.f, 171.f, 969.f, 3876.f, 11628.f, 27132.f, 50388.f, 75582.f,
        92378.f, 92378.f, 75582.f, 50388.f, 27132.f, 11628.f, 3876.f, 969.f,
        171.f, 19.f, 1.f};
    float g[OO];
    float a = tv, b = 1.f - tv;
    float v = 1.f;
#pragma unroll
    for (int q = 0; q < OO; ++q) { g[q] = v; v *= a; }
    v = 1.f;
#pragma unroll
    for (int q = OO - 1; q >= 0; --q) { g[q] = g[q] * v * binom[q]; v *= b; }
#pragma unroll
    for (int r = 0; r < 12; ++r) {
        int ql = (r & 3) + 8 * (r >> 2);
        int qh = ql + 4;
        float lo_v = g[ql];
        float hi_v = (qh < OO) ? g[qh] : 0.f;
        float s = hi ? hi_v : lo_v;
        gs[r] = sq ? s * s : s;
    }
}

__device__ __forceinline__ unsigned pack_pk(float x, float y) {
    union { fp16x2 h; unsigned u; } cv;
    cv.h = __builtin_amdgcn_cvt_pkrtz(x, y);
    return cv.u;
}

// ---------------------------------------------------------------------------
// Chain via MFMA: one wave = one (c,p) x 32 points. State cg[12] holds the
// gated f^T rows this half-wave owns (C layout: col n = lane&31,
// row q = (r&3)+8*(r>>2)+4*hi). Per step: pack to f16, half-wave exchange
// (shfl_xor 32) to build the B fragment (B[k=q][n], k=(lane>>5)*8+j), two
// 32x32x16 f16 MFMAs (K=20 padded to 32) against A=W^T, then gate.
// ---------------------------------------------------------------------------
__global__ __launch_bounds__(256) void chain_kernel(
    const float* __restrict__ X, const int* __restrict__ perm,
    const float* __restrict__ W0, const _Float16* __restrict__ WA,
    float* __restrict__ partial) {
    const int lane = threadIdx.x & 63;
    const int wv = threadIdx.x >> 6;
    const int nl = lane & 31;
    const bool hi = (lane >> 5) != 0;
    const int n0 = (blockIdx.x * 4 + wv) * 32;
    const int cp = blockIdx.y;
    const int c = cp / PP, p = cp % PP;
    const bool sq = (c != 0);

    // permuted X entries for this wave's 32 points (perm is wave-uniform)
    float t[DD];
#pragma unroll
    for (int i = 0; i < DD; ++i)
        t[i] = X[(size_t)(n0 + nl) * DD + perm[p * DD + i]];

    float gs[12], cg[12];
    gate_sel(t[0], sq, hi, gs);
    const float* w0r = W0 + (c * PP + p) * OO;   // wave-uniform row
#pragma unroll
    for (int r = 0; r < 12; ++r) {
        int ql = (r & 3) + 8 * (r >> 2);
        int qh = ql + 4;
        float wl = w0r[ql];
        float wh = (qh < OO) ? w0r[qh] : 0.f;
        cg[r] = (hi ? wh : wl) * gs[r];
    }

#pragma unroll
    for (int i = 1; i < DD; ++i) {
        // pack the 12 gated rows into 6 f16-pair dwords (q pairs (2e,2e+1))
        unsigned pk[6], qk[6];
#pragma unroll
        for (int e = 0; e < 6; ++e) pk[e] = pack_pk(cg[2 * e], cg[2 * e + 1]);
#pragma unroll
        for (int e = 0; e < 6; ++e) qk[e] = (unsigned)__shfl_xor((int)pk[e], 32, 64);

        // B fragment: dword e of MFMA m holds k = 16m + 8*hi + 2e, 2e+1
        // source reg pair = (k&2)/2 + 2*(k>>3), source half = (k>>2)&1
        union { unsigned u[4]; half8 h; } B0, B1;
        B0.u[0] = hi ? qk[2] : pk[0];
        B0.u[1] = hi ? qk[3] : pk[1];
        B0.u[2] = hi ? pk[2] : qk[0];
        B0.u[3] = hi ? pk[3] : qk[1];
        B1.u[0] = hi ? 0u : pk[4];
        B1.u[1] = hi ? 0u : pk[5];
        B1.u[2] = hi ? 0u : qk[4];   // q20..23: gated to exact zero
        B1.u[3] = hi ? 0u : qk[5];

        // A = W^T fragment: row m = q_out = lane&31, k = 8*hi + j (+16 for m=1)
        const _Float16* wa = WA + (size_t)(((c * (DD - 1)) + (i - 1)) * PP + p) * 1024;
        const _Float16* arow = wa + nl * 32 + (hi ? 8 : 0);
        half8 A0 = *(const half8*)(arow);
        half8 A1 = *(const half8*)(arow + 16);

        floatx16 acc = {};
        acc = __builtin_amdgcn_mfma_f32_32x32x16_f16(A0, B0.h, acc, 0, 0, 0);
        acc = __builtin_amdgcn_mfma_f32_32x32x16_f16(A1, B1.h, acc, 0, 0, 0);

        gate_sel(t[i], sq, hi, gs);
#pragma unroll
        for (int r = 0; r < 12; ++r) cg[r] = acc[r] * gs[r];
    }

    float s = 0.f;
#pragma unroll
    for (int r = 0; r < 12; ++r) s += cg[r];
    s += __shfl_xor(s, 32, 64);          // add the other half-wave's q rows
    if (lane < 32) partial[(size_t)cp * NPTS + n0 + nl] = s;
}

// ---------------------------------------------------------------------------
// Reduce: out[n][0] = sum_p mean; out[n][1] = sum_k coef[k] sum_p mom_k
// ---------------------------------------------------------------------------
__global__ void reduce_kernel(const float* __restrict__ partial,
                              float* __restrict__ out) {
    int n = blockIdx.x * 256 + threadIdx.x;
    float m = 0.f;
#pragma unroll
    for (int p = 0; p < PP; ++p) m += partial[p * NPTS + n];

    const float coef[NCHAIN] = {0.f, 1.f, 0.5f, 1.f / 6.f, 1.f / 24.f,
                                1.f / 120.f, 1.f / 720.f};
    float v = 0.f;
#pragma unroll
    for (int c = 1; c < NCHAIN; ++c) {
        float s = 0.f;
#pragma unroll
        for (int p = 0; p < PP; ++p) s += partial[(c * PP + p) * NPTS + n];
        v += coef[c] * s;
    }
    out[2 * n] = m;
    out[2 * n + 1] = v;
}

extern "C" void kernel_launch(void* const* d_in, const int* in_sizes, int n_in,
                              void* d_out, int out_size, void* d_ws, size_t ws_size,
                              hipStream_t stream) {
    const float* X      = (const float*)d_in[0];
    const int*   perm   = (const int*)d_in[1];
    const float* meanw0 = (const float*)d_in[2];
    const float* meanw  = (const float*)d_in[3];
    const float* varw0  = (const float*)d_in[4];
    const float* varw   = (const float*)d_in[5];
    float* out = (float*)d_out;

    // workspace: [W0: 2800 f32][WA: 1,003,520 f16][partial: 140*32768 f32]
    float*     W0      = (float*)d_ws;
    _Float16*  WA      = (_Float16*)((char*)d_ws + 11200);
    float*     partial = (float*)((char*)d_ws + 11200 + 2007040);

    int prep_n = NCHAIN * PP * OO + NCHAIN * (DD - 1) * PP * 32 * 32;
    hipLaunchKernelGGL(prep_kernel, dim3((prep_n + 255) / 256), dim3(256), 0,
                       stream, meanw0, meanw, varw0, varw, W0, WA);

    dim3 grid(NPTS / 128, NCHAIN * PP);   // 4 waves/block, 32 pts/wave
    hipLaunchKernelGGL(chain_kernel, grid, dim3(256), 0, stream,
                       X, perm, W0, WA, partial);

    hipLaunchKernelGGL(reduce_kernel, dim3(NPTS / 256), dim3(256), 0, stream,
                       partial, out);
}

// Round 5
// 207.727 us; speedup vs baseline: 5.3803x; 1.6567x over previous
//
#include <hip/hip_runtime.h>
#include <math.h>

#define NPTS 32768
#define DD 8
#define OO 20      // ORDER+1
#define PP 20
#define NCHAIN 7   // c=0: mean chain; c=1..6: variance moment k=c

typedef _Float16 half8 __attribute__((ext_vector_type(8)));
typedef __fp16 fp16x2 __attribute__((ext_vector_type(2)));
typedef float floatx16 __attribute__((ext_vector_type(16)));

// ---------------------------------------------------------------------------
// Prep:
//   W0[c][p][q]  fp32, = c==0 ? exp(meanw0) : exp(2*meanw0 + c*varw0)   (no binom)
//   WA[c][i][p][q][o] f16, 32x32 zero-padded, transposed exp'd weights.
// binom lives in the fp32 gate (binom up to 92378 > f16 max; basis in [0,1]).
// ---------------------------------------------------------------------------
__global__ void prep_kernel(const float* __restrict__ meanw0,
                            const float* __restrict__ meanw,
                            const float* __restrict__ varw0,
                            const float* __restrict__ varw,
                            float* __restrict__ W0,
                            _Float16* __restrict__ WA) {
    int e = blockIdx.x * 256 + threadIdx.x;
    const int n0 = NCHAIN * PP * OO;                 // 2800
    const int nW = NCHAIN * (DD - 1) * PP * 32 * 32; // 1,003,520
    if (e < n0) {
        int q = e % OO;
        int rem = e / OO;
        int p = rem % PP;
        int c = rem / PP;
        float m = meanw0[p * OO + q];
        W0[e] = (c == 0) ? __expf(m) : __expf(2.f * m + (float)c * varw0[p * OO + q]);
    } else if (e < n0 + nW) {
        int idx = e - n0;
        int o = idx & 31; idx >>= 5;
        int q = idx & 31; idx >>= 5;
        int p = idx % PP; idx /= PP;
        int i = idx % (DD - 1);
        int c = idx / (DD - 1);
        float v = 0.f;
        if (o < OO && q < OO) {
            int mi = ((i * PP + p) * OO + o) * OO + q;   // meanw[i][p][o][q]
            float m = meanw[mi];
            v = (c == 0) ? __expf(m) : __expf(2.f * m + (float)c * varw[mi]);
        }
        WA[e - n0] = (_Float16)v;
    }
}

// basis b_q = binom[q] t^q (1-t)^(19-q), fp32
__device__ __forceinline__ void basis20(float tv, float* g) {
    constexpr float binom[OO] = {
        1.f, 19.f, 171.f, 969.f, 3876.f, 11628.f, 27132.f, 50388.f, 75582.f,
        92378.f, 92378.f, 75582.f, 50388.f, 27132.f, 11628.f, 3876.f, 969.f,
        171.f, 19.f, 1.f};
    float a = tv, b = 1.f - tv, v = 1.f;
#pragma unroll
    for (int q = 0; q < OO; ++q) { g[q] = v; v *= a; }
    v = 1.f;
#pragma unroll
    for (int q = OO - 1; q >= 0; --q) { g[q] = g[q] * v * binom[q]; v *= b; }
}

__device__ __forceinline__ unsigned pack_pk(float x, float y) {
    union { fp16x2 h; unsigned u; } cv;
    cv.h = __builtin_amdgcn_cvt_pkrtz(x, y);
    return cv.u;
}

// ---------------------------------------------------------------------------
// One wave = one p x 32 points x ALL 7 chains. Basis computed once per step,
// shared: mean chain uses b, var chains use b^2 (per-chain math identical to
// the per-(c,p) version -> same rounding). C-layout state cg[c][12]
// (col n = lane&31, row q = (r&3)+8*(r>>2)+4*hi); per step per chain:
// pack f16, half-wave shfl_xor(32) -> B fragment, 2x mfma_32x32x16_f16
// against A=W^T, f32 gate apply.
// ---------------------------------------------------------------------------
__global__ __launch_bounds__(256, 2) void chain_kernel(
    const float* __restrict__ X, const int* __restrict__ perm,
    const float* __restrict__ W0, const _Float16* __restrict__ WA,
    float* __restrict__ partial) {
    const int lane = threadIdx.x & 63;
    const int wv = threadIdx.x >> 6;
    const int nl = lane & 31;
    const bool hi = (lane >> 5) != 0;
    const int n0 = (blockIdx.x * 4 + wv) * 32;
    const int p = blockIdx.y;

    // permuted X entries for this wave's 32 points (perm is wave-uniform)
    float t[DD];
#pragma unroll
    for (int i = 0; i < DD; ++i)
        t[i] = X[(size_t)(n0 + nl) * DD + perm[p * DD + i]];

    float cg[NCHAIN][12];

    // ---- init: f0 = W0row * gate(t0) ----
    {
        float g[OO];
        basis20(t[0], g);
        float gs[12], gq[12];
#pragma unroll
        for (int r = 0; r < 12; ++r) {
            int ql = (r & 3) + 8 * (r >> 2);
            int qh = ql + 4;
            float s = hi ? ((qh < OO) ? g[qh] : 0.f) : g[ql];
            gs[r] = s; gq[r] = s * s;
        }
#pragma unroll
        for (int c = 0; c < NCHAIN; ++c) {
            const float* w0r = W0 + (c * PP + p) * OO;
#pragma unroll
            for (int r = 0; r < 12; ++r) {
                int ql = (r & 3) + 8 * (r >> 2);
                int qh = ql + 4;
                float wsel = hi ? ((qh < OO) ? w0r[qh] : 0.f) : w0r[ql];
                cg[c][r] = wsel * (c == 0 ? gs[r] : gq[r]);
            }
        }
    }

    // per-lane A-operand offset (A row m = q_out = nl, k = hi*8 + j)
    const int aoff = nl * 32 + (hi ? 8 : 0);

#pragma unroll
    for (int i = 1; i < DD; ++i) {
        float g[OO];
        basis20(t[i], g);
        float gs[12], gq[12];
#pragma unroll
        for (int r = 0; r < 12; ++r) {
            int ql = (r & 3) + 8 * (r >> 2);
            int qh = ql + 4;
            float s = hi ? ((qh < OO) ? g[qh] : 0.f) : g[ql];
            gs[r] = s; gq[r] = s * s;
        }

#pragma unroll
        for (int c = 0; c < NCHAIN; ++c) {
            unsigned pk[6], qk[6];
#pragma unroll
            for (int e = 0; e < 6; ++e) pk[e] = pack_pk(cg[c][2 * e], cg[c][2 * e + 1]);
#pragma unroll
            for (int e = 0; e < 6; ++e) qk[e] = (unsigned)__shfl_xor((int)pk[e], 32, 64);

            union { unsigned u[4]; half8 h; } B0, B1;
            B0.u[0] = hi ? qk[2] : pk[0];
            B0.u[1] = hi ? qk[3] : pk[1];
            B0.u[2] = hi ? pk[2] : qk[0];
            B0.u[3] = hi ? pk[3] : qk[1];
            B1.u[0] = hi ? 0u : pk[4];
            B1.u[1] = hi ? 0u : pk[5];
            B1.u[2] = hi ? 0u : qk[4];   // q20..23: gated to exact zero
            B1.u[3] = hi ? 0u : qk[5];

            const _Float16* wa =
                WA + (size_t)(((c * (DD - 1)) + (i - 1)) * PP + p) * 1024 + aoff;
            half8 A0 = *(const half8*)(wa);
            half8 A1 = *(const half8*)(wa + 16);

            floatx16 acc = {};
            acc = __builtin_amdgcn_mfma_f32_32x32x16_f16(A0, B0.h, acc, 0, 0, 0);
            acc = __builtin_amdgcn_mfma_f32_32x32x16_f16(A1, B1.h, acc, 0, 0, 0);

#pragma unroll
            for (int r = 0; r < 12; ++r)
                cg[c][r] = acc[r] * (c == 0 ? gs[r] : gq[r]);
        }
    }

    // ---- epilogue: mean = sum(chain0); var = sum_c coef[c]*sum(chain c) ----
    const float coef[NCHAIN] = {0.f, 1.f, 0.5f, 1.f / 6.f, 1.f / 24.f,
                                1.f / 120.f, 1.f / 720.f};
    float sm = 0.f;
#pragma unroll
    for (int r = 0; r < 12; ++r) sm += cg[0][r];
    float sv = 0.f;
#pragma unroll
    for (int c = 1; c < NCHAIN; ++c) {
        float s = 0.f;
#pragma unroll
        for (int r = 0; r < 12; ++r) s += cg[c][r];
        sv += coef[c] * s;
    }
    sm += __shfl_xor(sm, 32, 64);
    sv += __shfl_xor(sv, 32, 64);
    if (lane < 32) {
        partial[(size_t)p * NPTS + n0 + nl] = sm;
        partial[(size_t)(PP + p) * NPTS + n0 + nl] = sv;
    }
}

// ---------------------------------------------------------------------------
// Reduce over p: out[n][0] = sum_p mean_p[n]; out[n][1] = sum_p var_p[n]
// ---------------------------------------------------------------------------
__global__ void reduce_kernel(const float* __restrict__ partial,
                              float* __restrict__ out) {
    int n = blockIdx.x * 256 + threadIdx.x;
    float m = 0.f, v = 0.f;
#pragma unroll
    for (int p = 0; p < PP; ++p) {
        m += partial[(size_t)p * NPTS + n];
        v += partial[(size_t)(PP + p) * NPTS + n];
    }
    out[2 * n] = m;
    out[2 * n + 1] = v;
}

extern "C" void kernel_launch(void* const* d_in, const int* in_sizes, int n_in,
                              void* d_out, int out_size, void* d_ws, size_t ws_size,
                              hipStream_t stream) {
    const float* X      = (const float*)d_in[0];
    const int*   perm   = (const int*)d_in[1];
    const float* meanw0 = (const float*)d_in[2];
    const float* meanw  = (const float*)d_in[3];
    const float* varw0  = (const float*)d_in[4];
    const float* varw   = (const float*)d_in[5];
    float* out = (float*)d_out;

    // workspace: [W0: 2800 f32][WA: 1,003,520 f16][partial: 2*20*32768 f32]
    float*     W0      = (float*)d_ws;
    _Float16*  WA      = (_Float16*)((char*)d_ws + 11200);
    float*     partial = (float*)((char*)d_ws + 11200 + 2007040);

    int prep_n = NCHAIN * PP * OO + NCHAIN * (DD - 1) * PP * 32 * 32;
    hipLaunchKernelGGL(prep_kernel, dim3((prep_n + 255) / 256), dim3(256), 0,
                       stream, meanw0, meanw, varw0, varw, W0, WA);

    dim3 grid(NPTS / 128, PP);   // 4 waves/block, 32 pts/wave, all 7 chains/wave
    hipLaunchKernelGGL(chain_kernel, grid, dim3(256), 0, stream,
                       X, perm, W0, WA, partial);

    hipLaunchKernelGGL(reduce_kernel, dim3(NPTS / 256), dim3(256), 0, stream,
                       partial, out);
}